// Round 5
// baseline (438.150 us; speedup 1.0000x reference)
//
#include <hip/hip_runtime.h>

typedef unsigned short u16;
typedef unsigned int u32;
typedef __attribute__((ext_vector_type(8))) short s16x8;
typedef __attribute__((ext_vector_type(4))) float f32x4;

__device__ __forceinline__ float bf2f(u32 u) {
    return __uint_as_float(u << 16);
}
__device__ __forceinline__ u16 f2bf(float f) {
    u32 x = __float_as_uint(f);
    u32 r = (x + 0x7fffu + ((x >> 16) & 1u)) >> 16;   // round-nearest-even
    return (u16)r;
}

__device__ __forceinline__ void gload16(const u16* g, u16* l) {
    __builtin_amdgcn_global_load_lds(
        (const __attribute__((address_space(1))) unsigned int*)g,
        (__attribute__((address_space(3))) unsigned int*)l,
        16, 0, 0);
}

// ---------------------------------------------------------------- prep
__global__ __launch_bounds__(256) void cvtx_k(
    const float* __restrict__ x, u16* __restrict__ xb, int N, int Mp)
{
    const int i = blockIdx.x * 256 + threadIdx.x;
    if (i >= Mp * 96) return;
    const int r = i / 96, c = i - r * 96;
    float v = (r < N && c < 75) ? x[(size_t)r * 75 + c] : 0.f;
    xb[i] = f2bf(v);
}

__global__ __launch_bounds__(256) void cvtw_k(
    const float* __restrict__ W, u16* __restrict__ Wt, int K, int Kp, int Ncol)
{
    const int i = blockIdx.x * 256 + threadIdx.x;
    if (i >= Ncol * Kp) return;
    const int n = i / Kp, k = i - n * Kp;
    Wt[i] = f2bf(k < K ? W[(size_t)k * Ncol + n] : 0.f);
}

// ---------------------------------------------------------------- MFMA GEMM
__global__ __launch_bounds__(256) void mgemm_k(
    const u16* __restrict__ A, const u16* __restrict__ Bt,
    u16* __restrict__ C, int M, int K, int Ncol)
{
    __shared__ u16 Al[128 * 32];
    __shared__ u16 Bl[128 * 32];
    const int t = threadIdx.x;
    const int lane = t & 63;
    const int wid = t >> 6;
    const int wr = wid >> 1, wc = wid & 1;
    const int rr = lane & 15, q = lane >> 4;
    const int m0 = blockIdx.y * 128, n0 = blockIdx.x * 128;

    f32x4 acc[4][4];
#pragma unroll
    for (int m = 0; m < 4; ++m)
#pragma unroll
        for (int n = 0; n < 4; ++n) acc[m][n] = (f32x4){0.f, 0.f, 0.f, 0.f};

    const int nk = K >> 5;
    for (int kt = 0; kt < nk; ++kt) {
        const int k0 = kt << 5;
#pragma unroll
        for (int i = 0; i < 2; ++i) {
            const int si = i * 256 + t;
            const int r = si >> 2, s = si & 3;
            const int g = s ^ ((r >> 1) & 3);
            gload16(A  + (size_t)(m0 + r) * K + k0 + g * 8, &Al[si * 8]);
            gload16(Bt + (size_t)(n0 + r) * K + k0 + g * 8, &Bl[si * 8]);
        }
        __syncthreads();
        s16x8 af[4], bf[4];
#pragma unroll
        for (int m = 0; m < 4; ++m) {
            const int r = wr * 64 + m * 16 + rr;
            af[m] = *reinterpret_cast<const s16x8*>(&Al[r * 32 + ((q ^ ((r >> 1) & 3)) << 3)]);
        }
#pragma unroll
        for (int n = 0; n < 4; ++n) {
            const int r = wc * 64 + n * 16 + rr;
            bf[n] = *reinterpret_cast<const s16x8*>(&Bl[r * 32 + ((q ^ ((r >> 1) & 3)) << 3)]);
        }
#pragma unroll
        for (int m = 0; m < 4; ++m)
#pragma unroll
            for (int n = 0; n < 4; ++n)
                acc[m][n] = __builtin_amdgcn_mfma_f32_16x16x32_bf16(af[m], bf[n], acc[m][n], 0, 0, 0);
        __syncthreads();
    }
#pragma unroll
    for (int m = 0; m < 4; ++m) {
        const int row_b = m0 + wr * 64 + m * 16 + q * 4;
#pragma unroll
        for (int j = 0; j < 4; ++j) {
            const int row = row_b + j;
            if (row < M) {
#pragma unroll
                for (int n = 0; n < 4; ++n) {
                    const int col = n0 + wc * 64 + n * 16 + rr;
                    C[(size_t)row * Ncol + col] = f2bf(acc[m][n][j]);
                }
            }
        }
    }
}

// ---------------------------------------------------------------- logits (per node)
template<int CH, int C>
__global__ __launch_bounds__(256) void logits_k(
    const u16* __restrict__ h, const float* __restrict__ a_s,
    const float* __restrict__ a_d, float* __restrict__ als,
    float* __restrict__ ald, int N)
{
    constexpr int HH = CH / C;
    constexpr int Kc = CH / 64;
    const int lane = threadIdx.x & 63;
    const int n = blockIdx.x * 4 + (threadIdx.x >> 6);
    if (n >= N) return;
    const int ch0 = Kc * lane;
    float vv[Kc];
    const u16* hp = h + (size_t)n * CH + ch0;
    if constexpr (Kc == 8) {
        const int4 r = *reinterpret_cast<const int4*>(hp);
        const u32 rr[4] = {(u32)r.x, (u32)r.y, (u32)r.z, (u32)r.w};
#pragma unroll
        for (int qq = 0; qq < 4; ++qq) { vv[2*qq] = bf2f(rr[qq] & 0xffffu); vv[2*qq+1] = bf2f(rr[qq] >> 16); }
    } else {
        const u32 r = *reinterpret_cast<const u32*>(hp);
        vv[0] = bf2f(r & 0xffffu); vv[1] = bf2f(r >> 16);
    }
    float ps = 0.f, pd = 0.f;
#pragma unroll
    for (int j = 0; j < Kc; ++j) {
        ps += vv[j] * a_s[ch0 + j];
        pd += vv[j] * a_d[ch0 + j];
    }
    constexpr int Gs = 64 / HH;
#pragma unroll
    for (int off = Gs >> 1; off; off >>= 1) {
        ps += __shfl_xor(ps, off, 64);
        pd += __shfl_xor(pd, off, 64);
    }
    const int hd = ch0 / C;
    if ((lane & (Gs - 1)) == 0) {
        als[(size_t)n * HH + hd] = ps;
        ald[(size_t)n * HH + hd] = pd;
    }
}

// ---------------------------------------------------------------- CSR build
__global__ void count_k(const int* __restrict__ edst, int* __restrict__ cnt, int E_, int N_)
{
    const int i = blockIdx.x * 256 + threadIdx.x;
    if (i >= E_ + N_) return;
    const int d = (i < E_) ? edst[i] : (i - E_);
    atomicAdd(&cnt[d], 1);
}

#define SCAN_B 256
__global__ void scan1_k(const int* __restrict__ cnt, int* __restrict__ part,
                        int* __restrict__ bsum, int n)
{
    __shared__ int sm[SCAN_B];
    const int idx = blockIdx.x * SCAN_B + threadIdx.x;
    int v = (idx < n) ? cnt[idx] : 0;
    sm[threadIdx.x] = v;
    __syncthreads();
    for (int off = 1; off < SCAN_B; off <<= 1) {
        int t2 = (threadIdx.x >= off) ? sm[threadIdx.x - off] : 0;
        __syncthreads();
        sm[threadIdx.x] += t2;
        __syncthreads();
    }
    if (idx < n) part[idx] = sm[threadIdx.x];
    if (threadIdx.x == SCAN_B - 1) bsum[blockIdx.x] = sm[threadIdx.x];
}

__global__ void scan2_k(int* __restrict__ bsum, int nb)
{
    __shared__ int sm[SCAN_B];
    const int t = threadIdx.x;
    int v = (t < nb) ? bsum[t] : 0;
    sm[t] = v;
    __syncthreads();
    for (int off = 1; off < SCAN_B; off <<= 1) {
        int t2 = (t >= off) ? sm[t - off] : 0;
        __syncthreads();
        sm[t] += t2;
        __syncthreads();
    }
    if (t < nb) bsum[t] = sm[t] - v;   // exclusive
}

__global__ void scan3_k(const int* __restrict__ part, const int* __restrict__ boff,
                        int* __restrict__ offs, int n)
{
    const int idx = blockIdx.x * SCAN_B + threadIdx.x;
    if (idx < n) offs[idx + 1] = part[idx] + boff[idx / SCAN_B];
    if (idx == 0) offs[0] = 0;
}

__global__ void scatter_k(const int* __restrict__ esrc, const int* __restrict__ edst,
                          const int* __restrict__ offs, int* __restrict__ fill,
                          int* __restrict__ csr, int* __restrict__ csrd,
                          int E_, int N_)
{
    const int i = blockIdx.x * 256 + threadIdx.x;
    if (i >= E_ + N_) return;
    int s, d;
    if (i < E_) { s = esrc[i]; d = edst[i]; } else { s = d = i - E_; }
    const int pos = offs[d] + atomicAdd(&fill[d], 1);
    csr[pos] = s;
    csrd[pos] = d;
}

// ---------------------------------------------------------------- edge logits
// expe[slot][h] = exp(min(leaky(als[src]+ald[dst]), 60)); CSR-slot order, coalesced.
template<int HH>
__global__ __launch_bounds__(256) void elogit_k(
    const int* __restrict__ csr, const int* __restrict__ csrd,
    const float* __restrict__ als, const float* __restrict__ ald,
    float* __restrict__ expe, int ET)
{
    const int i = blockIdx.x * 256 + threadIdx.x;
    if (i >= ET) return;
    const int s = csr[i], d = csrd[i];
    if constexpr (HH == 4) {
        const float4 a = *reinterpret_cast<const float4*>(&als[(size_t)s * 4]);
        const float4 b = *reinterpret_cast<const float4*>(&ald[(size_t)d * 4]);
        float ev[4] = {a.x + b.x, a.y + b.y, a.z + b.z, a.w + b.w};
        float4 o;
        float* op = &o.x;
#pragma unroll
        for (int h = 0; h < 4; ++h) {
            float e = ev[h]; e = (e > 0.f) ? e : 0.2f * e;
            op[h] = __expf(fminf(e, 60.f));
        }
        *reinterpret_cast<float4*>(&expe[(size_t)i * 4]) = o;
    } else {
        float e = als[s] + ald[d]; e = (e > 0.f) ? e : 0.2f * e;
        expe[i] = __expf(fminf(e, 60.f));
    }
}

// ---------------------------------------------------------------- aggregate+BN(+ReLU)
// one wave per dst node. Sweep 1: coalesced denom from expe. Sweep 2: gather,
// 8 edges in flight, alpha = expe[slot]*inv (no exp in chain).
template<int CH, int C, bool RELU>
__global__ __launch_bounds__(256) void agg_k(
    const u16* __restrict__ hsrc, const int* __restrict__ offs,
    const int* __restrict__ csr, const float* __restrict__ expe,
    const float* __restrict__ bias,
    const float* __restrict__ gam, const float* __restrict__ bet,
    const float* __restrict__ rmean, const float* __restrict__ rvar,
    u16* __restrict__ outp, int N)
{
    constexpr int HH = CH / C;
    constexpr int Kc = CH / 64;
    const int lane = threadIdx.x & 63;
    const int dst = blockIdx.x * 4 + (threadIdx.x >> 6);
    if (dst >= N) return;
    const int ch0 = Kc * lane;
    const int hd = ch0 / C;

    const int rs = offs[dst], re = offs[dst + 1];

    // sweep 1: denom (coalesced reads of expe in slot order)
    float smv[HH];
#pragma unroll
    for (int h = 0; h < HH; ++h) smv[h] = 0.f;
    for (int s = rs + lane; s < re; s += 64) {
        if constexpr (HH == 4) {
            const float4 v = *reinterpret_cast<const float4*>(&expe[(size_t)s * 4]);
            smv[0] += v.x; smv[1] += v.y; smv[2] += v.z; smv[3] += v.w;
        } else {
            smv[0] += expe[s];
        }
    }
#pragma unroll
    for (int h = 0; h < HH; ++h)
#pragma unroll
        for (int off = 32; off; off >>= 1) smv[h] += __shfl_xor(smv[h], off, 64);
    const float invh = 1.f / (smv[hd] + 1e-16f);

    // sweep 2: weighted gather, 8 edges in flight
    float acc[Kc] = {};
    int s = rs;
#define GATH_ROUND(U)                                                            \
    for (; s + U <= re; s += U) {                                                \
        int sn[U];                                                               \
        _Pragma("unroll")                                                        \
        for (int u = 0; u < U; ++u) sn[u] = csr[s + u];                          \
        float aa[U];                                                             \
        _Pragma("unroll")                                                        \
        for (int u = 0; u < U; ++u)                                              \
            aa[u] = expe[(size_t)(s + u) * HH + hd] * invh;                      \
        if constexpr (Kc == 8) {                                                 \
            int4 r[U];                                                           \
            _Pragma("unroll")                                                    \
            for (int u = 0; u < U; ++u)                                          \
                r[u] = *reinterpret_cast<const int4*>(hsrc + (size_t)sn[u] * CH + ch0); \
            _Pragma("unroll")                                                    \
            for (int u = 0; u < U; ++u) {                                        \
                const u32 rr2[4] = {(u32)r[u].x, (u32)r[u].y, (u32)r[u].z, (u32)r[u].w}; \
                _Pragma("unroll")                                                \
                for (int qq = 0; qq < 4; ++qq) {                                 \
                    acc[2*qq]   += aa[u] * bf2f(rr2[qq] & 0xffffu);              \
                    acc[2*qq+1] += aa[u] * bf2f(rr2[qq] >> 16);                  \
                }                                                                \
            }                                                                    \
        } else {                                                                 \
            u32 r[U];                                                            \
            _Pragma("unroll")                                                    \
            for (int u = 0; u < U; ++u)                                          \
                r[u] = *reinterpret_cast<const u32*>(hsrc + (size_t)sn[u] * CH + ch0); \
            _Pragma("unroll")                                                    \
            for (int u = 0; u < U; ++u) {                                        \
                acc[0] += aa[u] * bf2f(r[u] & 0xffffu);                          \
                acc[1] += aa[u] * bf2f(r[u] >> 16);                              \
            }                                                                    \
        }                                                                        \
    }
    GATH_ROUND(8)
    GATH_ROUND(1)
#undef GATH_ROUND

    // epilogue: +bias, BN (eval), optional ReLU, store bf16
    u16 ob[Kc];
#pragma unroll
    for (int j = 0; j < Kc; ++j) {
        const int ch = ch0 + j;
        const float scale = gam[ch] * rsqrtf(rvar[ch] + 1e-5f);
        float val = (acc[j] + bias[ch] - rmean[ch]) * scale + bet[ch];
        if (RELU) val = fmaxf(val, 0.f);
        ob[j] = f2bf(val);
    }
    u16* op = outp + (size_t)dst * CH + ch0;
    if constexpr (Kc == 8) {
        int4 w;
        w.x = (int)((u32)ob[0] | ((u32)ob[1] << 16));
        w.y = (int)((u32)ob[2] | ((u32)ob[3] << 16));
        w.z = (int)((u32)ob[4] | ((u32)ob[5] << 16));
        w.w = (int)((u32)ob[6] | ((u32)ob[7] << 16));
        *reinterpret_cast<int4*>(op) = w;
    } else {
        *reinterpret_cast<u32*>(op) = (u32)ob[0] | ((u32)ob[1] << 16);
    }
}

// ---------------------------------------------------------------- pool
__global__ __launch_bounds__(128) void pool_k(
    const u16* __restrict__ h3, const int* __restrict__ batch,
    float* __restrict__ out, int N)
{
    const int g = blockIdx.x;
    const int t = threadIdx.x;
    int lo = 0, hi = N;
    while (lo < hi) { int mid = (lo + hi) >> 1; if (batch[mid] < g) lo = mid + 1; else hi = mid; }
    const int s0 = lo;
    lo = 0; hi = N;
    while (lo < hi) { int mid = (lo + hi) >> 1; if (batch[mid] < g + 1) lo = mid + 1; else hi = mid; }
    const int s1 = lo;
    float sum = 0.f, mx = -1e30f;
    for (int n = s0; n < s1; ++n) {
        const float v = bf2f((u32)h3[(size_t)n * 128 + t]);
        sum += v;
        mx = fmaxf(mx, v);
    }
    const int cnt = s1 - s0;
    out[(size_t)g * 256 + t]       = cnt ? sum / (float)cnt : 0.f;
    out[(size_t)g * 256 + 128 + t] = cnt ? mx : 0.f;
}

// ---------------------------------------------------------------- launch
extern "C" void kernel_launch(void* const* d_in, const int* in_sizes, int n_in,
                              void* d_out, int out_size, void* d_ws, size_t ws_size,
                              hipStream_t stream)
{
    const float* x   = (const float*)d_in[0];
    const int* ei    = (const int*)d_in[1];
    const int* batch = (const int*)d_in[2];
    const float* W1  = (const float*)d_in[3];
    const float* as1 = (const float*)d_in[4];
    const float* ad1 = (const float*)d_in[5];
    const float* b1  = (const float*)d_in[6];
    const float* g1  = (const float*)d_in[7];
    const float* bt1 = (const float*)d_in[8];
    const float* rm1 = (const float*)d_in[9];
    const float* rv1 = (const float*)d_in[10];
    const float* W2  = (const float*)d_in[11];
    const float* as2 = (const float*)d_in[12];
    const float* ad2 = (const float*)d_in[13];
    const float* b2  = (const float*)d_in[14];
    const float* g2  = (const float*)d_in[15];
    const float* bt2 = (const float*)d_in[16];
    const float* rm2 = (const float*)d_in[17];
    const float* rv2 = (const float*)d_in[18];
    const float* W3  = (const float*)d_in[19];
    const float* as3 = (const float*)d_in[20];
    const float* ad3 = (const float*)d_in[21];
    const float* b3  = (const float*)d_in[22];
    const float* g3  = (const float*)d_in[23];
    const float* bt3 = (const float*)d_in[24];
    const float* rm3 = (const float*)d_in[25];
    const float* rv3 = (const float*)d_in[26];

    const int Nn = in_sizes[2];           // 50000
    const int Ee = in_sizes[1] / 2;       // 400000
    const int ET = Ee + Nn;               // + self-loops
    const int Gg = out_size / 256;        // 512
    const int Mp = ((Nn + 127) / 128) * 128;   // padded rows

    // workspace carve-up (256B aligned)
    char* ws = (char*)d_ws;
    size_t o = 0;
    auto alc = [&](size_t bytes) { size_t r = o; o = (o + bytes + 255) & ~(size_t)255; return r; };
    u16*  hA   = (u16*)(ws + alc((size_t)Mp * 512 * 2));
    u16*  hB   = (u16*)(ws + alc((size_t)Mp * 512 * 2));
    u16*  xb   = (u16*)(ws + alc((size_t)Mp * 96 * 2));
    u16*  Wt1  = (u16*)(ws + alc((size_t)512 * 96 * 2));
    u16*  Wt2  = (u16*)(ws + alc((size_t)512 * 512 * 2));
    u16*  Wt3  = (u16*)(ws + alc((size_t)128 * 512 * 2));
    float* als = (float*)(ws + alc((size_t)Nn * 4 * 4));
    float* ald = (float*)(ws + alc((size_t)Nn * 4 * 4));
    int*  cnt  = (int*)(ws + alc((size_t)2 * Nn * 4));
    int*  fill = cnt + Nn;
    int*  offs = (int*)(ws + alc((size_t)(Nn + 1) * 4));
    int*  part = (int*)(ws + alc((size_t)Nn * 4));
    int*  bsum = (int*)(ws + alc((size_t)SCAN_B * 4));
    int*  csr  = (int*)(ws + alc((size_t)ET * 4));
    int*  csrd = (int*)(ws + alc((size_t)ET * 4));
    float* expe = (float*)(ws + alc((size_t)ET * 4 * 4));
    (void)ws_size; (void)n_in;

    // ---- CSR by dst
    hipMemsetAsync(cnt, 0, (size_t)2 * Nn * 4, stream);
    const int ETB = (ET + 255) / 256;
    count_k<<<ETB, 256, 0, stream>>>(ei + Ee, cnt, Ee, Nn);
    const int nb = (Nn + SCAN_B - 1) / SCAN_B;
    scan1_k<<<nb, SCAN_B, 0, stream>>>(cnt, part, bsum, Nn);
    scan2_k<<<1, SCAN_B, 0, stream>>>(bsum, nb);
    scan3_k<<<nb, SCAN_B, 0, stream>>>(part, bsum, offs, Nn);
    scatter_k<<<ETB, 256, 0, stream>>>(ei, ei + Ee, offs, fill, csr, csrd, Ee, Nn);

    // ---- bf16 prep
    cvtx_k<<<(Mp * 96 + 255) / 256, 256, 0, stream>>>(x, xb, Nn, Mp);
    cvtw_k<<<(512 * 96 + 255) / 256, 256, 0, stream>>>(W1, Wt1, 75, 96, 512);
    cvtw_k<<<(512 * 512 + 255) / 256, 256, 0, stream>>>(W2, Wt2, 512, 512, 512);
    cvtw_k<<<(128 * 512 + 255) / 256, 256, 0, stream>>>(W3, Wt3, 512, 512, 128);

    const int nwb = (Nn + 3) / 4;
    const int mb = Mp / 128;

    // ---- layer 1
    {
        dim3 grid(4, mb);
        mgemm_k<<<grid, 256, 0, stream>>>(xb, Wt1, hA, Nn, 96, 512);
        logits_k<512, 128><<<nwb, 256, 0, stream>>>(hA, as1, ad1, als, ald, Nn);
        elogit_k<4><<<ETB, 256, 0, stream>>>(csr, csrd, als, ald, expe, ET);
        agg_k<512, 128, true><<<nwb, 256, 0, stream>>>(hA, offs, csr, expe,
                                                       b1, g1, bt1, rm1, rv1, hB, Nn);
    }
    // ---- layer 2
    {
        dim3 grid(4, mb);
        mgemm_k<<<grid, 256, 0, stream>>>(hB, Wt2, hA, Nn, 512, 512);
        logits_k<512, 128><<<nwb, 256, 0, stream>>>(hA, as2, ad2, als, ald, Nn);
        elogit_k<4><<<ETB, 256, 0, stream>>>(csr, csrd, als, ald, expe, ET);
        agg_k<512, 128, true><<<nwb, 256, 0, stream>>>(hA, offs, csr, expe,
                                                       b2, g2, bt2, rm2, rv2, hB, Nn);
    }
    // ---- layer 3
    {
        dim3 grid(1, mb);
        mgemm_k<<<grid, 256, 0, stream>>>(hB, Wt3, hA, Nn, 512, 128);
        logits_k<128, 128><<<nwb, 256, 0, stream>>>(hA, as3, ad3, als, ald, Nn);
        elogit_k<1><<<ETB, 256, 0, stream>>>(csr, csrd, als, ald, expe, ET);
        agg_k<128, 128, false><<<nwb, 256, 0, stream>>>(hA, offs, csr, expe,
                                                        b3, g3, bt3, rm3, rv3, hB, Nn);
    }
    // ---- global mean+max pool
    pool_k<<<Gg, 128, 0, stream>>>(hB, batch, (float*)d_out, Nn);
}

// Round 6
// 401.450 us; speedup vs baseline: 1.0914x; 1.0914x over previous
//
#include <hip/hip_runtime.h>

typedef unsigned short u16;
typedef unsigned int u32;
typedef __attribute__((ext_vector_type(8))) short s16x8;
typedef __attribute__((ext_vector_type(4))) float f32x4;

__device__ __forceinline__ float bf2f(u32 u) {
    return __uint_as_float(u << 16);
}
__device__ __forceinline__ u16 f2bf(float f) {
    u32 x = __float_as_uint(f);
    u32 r = (x + 0x7fffu + ((x >> 16) & 1u)) >> 16;   // round-nearest-even
    return (u16)r;
}

__device__ __forceinline__ void gload16(const u16* g, u16* l) {
    __builtin_amdgcn_global_load_lds(
        (const __attribute__((address_space(1))) unsigned int*)g,
        (__attribute__((address_space(3))) unsigned int*)l,
        16, 0, 0);
}

// ---------------------------------------------------------------- prep
__global__ __launch_bounds__(256) void cvtx_k(
    const float* __restrict__ x, u16* __restrict__ xb, int N, int Mp)
{
    const int i = blockIdx.x * 256 + threadIdx.x;
    if (i >= Mp * 96) return;
    const int r = i / 96, c = i - r * 96;
    float v = (r < N && c < 75) ? x[(size_t)r * 75 + c] : 0.f;
    xb[i] = f2bf(v);
}

__global__ __launch_bounds__(256) void cvtw_k(
    const float* __restrict__ W, u16* __restrict__ Wt, int K, int Kp, int Ncol)
{
    const int i = blockIdx.x * 256 + threadIdx.x;
    if (i >= Ncol * Kp) return;
    const int n = i / Kp, k = i - n * Kp;
    Wt[i] = f2bf(k < K ? W[(size_t)k * Ncol + n] : 0.f);
}

// ---------------------------------------------------------------- MFMA GEMM + fused logits
// C[M,Ncol] = A[M,K] @ Bt[Ncol,K]^T ; bf16, fp32 accum. 128x128 tile, BK=32,
// 4 waves (each 64x64 = 4x4 frags). Double-buffered LDS, prefetch next K-tile
// before compute (one barrier per K-step). XCD-swizzled 1-D grid: the NXB
// col-blocks sharing an A-panel land on the same XCD (L2 A-reuse).
// Epilogue also computes als/ald[row][head] (head = col-block, 128 ch/head).
__global__ __launch_bounds__(256) void mgemm_k(
    const u16* __restrict__ A, const u16* __restrict__ Bt, u16* __restrict__ C,
    const float* __restrict__ avs, const float* __restrict__ avd,
    float* __restrict__ als, float* __restrict__ ald,
    int M, int K, int Ncol, int H, int NXB)
{
    __shared__ u16 Al[2][128 * 32];
    __shared__ u16 Bl[2][128 * 32];
    const int t = threadIdx.x;
    const int lane = t & 63;
    const int wid = t >> 6;
    const int wr = wid >> 1, wc = wid & 1;
    const int rr = lane & 15, q = lane >> 4;

    // XCD-aware swizzle: grid = NXB * GY blocks, GY divisible by 8.
    const int dd = blockIdx.x;
    const int xcd = dd & 7, ii = dd >> 3;
    const int gpx = (int)(gridDim.x >> 3) / NXB;       // row-panels per XCD
    const int yb = xcd * gpx + ((NXB == 4) ? (ii >> 2) : ii);
    const int head = (NXB == 4) ? (ii & 3) : 0;
    const int m0 = yb * 128, n0 = head * 128;

    f32x4 acc[4][4];
#pragma unroll
    for (int m = 0; m < 4; ++m)
#pragma unroll
        for (int n = 0; n < 4; ++n) acc[m][n] = (f32x4){0.f, 0.f, 0.f, 0.f};

    auto stage = [&](int b, int k0) {
#pragma unroll
        for (int i2 = 0; i2 < 2; ++i2) {
            const int si = i2 * 256 + t;
            const int r = si >> 2, s = si & 3;
            const int g = s ^ ((r >> 1) & 3);
            gload16(A  + (size_t)(m0 + r) * K + k0 + g * 8, &Al[b][si * 8]);
            gload16(Bt + (size_t)(n0 + r) * K + k0 + g * 8, &Bl[b][si * 8]);
        }
    };

    const int nk = K >> 5;
    stage(0, 0);
    __syncthreads();
    int buf = 0;
    for (int kt = 0; kt < nk; ++kt) {
        if (kt + 1 < nk) stage(buf ^ 1, (kt + 1) << 5);   // prefetch next
        s16x8 af[4], bfr[4];
#pragma unroll
        for (int m = 0; m < 4; ++m) {
            const int r = wr * 64 + m * 16 + rr;
            af[m] = *reinterpret_cast<const s16x8*>(&Al[buf][r * 32 + ((q ^ ((r >> 1) & 3)) << 3)]);
        }
#pragma unroll
        for (int n = 0; n < 4; ++n) {
            const int r = wc * 64 + n * 16 + rr;
            bfr[n] = *reinterpret_cast<const s16x8*>(&Bl[buf][r * 32 + ((q ^ ((r >> 1) & 3)) << 3)]);
        }
#pragma unroll
        for (int m = 0; m < 4; ++m)
#pragma unroll
            for (int n = 0; n < 4; ++n)
                acc[m][n] = __builtin_amdgcn_mfma_f32_16x16x32_bf16(af[m], bfr[n], acc[m][n], 0, 0, 0);
        __syncthreads();   // next buf ready; current buf free
        buf ^= 1;
    }

    // ---- h write: C row = (lane>>4)*4+j, col = lane&15 within each fragment
#pragma unroll
    for (int m = 0; m < 4; ++m) {
        const int row_b = m0 + wr * 64 + m * 16 + q * 4;
#pragma unroll
        for (int j = 0; j < 4; ++j) {
            const int row = row_b + j;
            if (row < M) {
#pragma unroll
                for (int n = 0; n < 4; ++n) {
                    const int col = n0 + wc * 64 + n * 16 + rr;
                    C[(size_t)row * Ncol + col] = f2bf(acc[m][n][j]);
                }
            }
        }
    }

    // ---- fused logits: als/ald[row][head] = sum_c acc_row[c] * a[head][c]
    float asv[4], adv[4];
#pragma unroll
    for (int n = 0; n < 4; ++n) {
        const int c = wc * 64 + n * 16 + rr;
        asv[n] = avs[head * 128 + c];
        adv[n] = avd[head * 128 + c];
    }
    float* lps = (float*)&Al[0][0];        // [2][128]
    float* lpd = lps + 256;
#pragma unroll
    for (int m = 0; m < 4; ++m)
#pragma unroll
        for (int j = 0; j < 4; ++j) {
            float ps = 0.f, pd = 0.f;
#pragma unroll
            for (int n = 0; n < 4; ++n) {
                ps += acc[m][n][j] * asv[n];
                pd += acc[m][n][j] * adv[n];
            }
#pragma unroll
            for (int off = 1; off < 16; off <<= 1) {
                ps += __shfl_xor(ps, off, 64);
                pd += __shfl_xor(pd, off, 64);
            }
            if (rr == 0) {
                const int r = wr * 64 + m * 16 + q * 4 + j;
                lps[wc * 128 + r] = ps;
                lpd[wc * 128 + r] = pd;
            }
        }
    __syncthreads();
    if (t < 128) {
        const int row = m0 + t;
        if (row < M) {
            als[(size_t)row * H + head] = lps[t] + lps[128 + t];
            ald[(size_t)row * H + head] = lpd[t] + lpd[128 + t];
        }
    }
}

// ---------------------------------------------------------------- CSR build
__global__ void count_k(const int* __restrict__ edst, int* __restrict__ cnt, int E_, int N_)
{
    const int i = blockIdx.x * 256 + threadIdx.x;
    if (i >= E_ + N_) return;
    const int d = (i < E_) ? edst[i] : (i - E_);
    atomicAdd(&cnt[d], 1);
}

#define SCAN_B 256
__global__ void scan1_k(const int* __restrict__ cnt, int* __restrict__ part,
                        int* __restrict__ bsum, int n)
{
    __shared__ int sm[SCAN_B];
    const int idx = blockIdx.x * SCAN_B + threadIdx.x;
    int v = (idx < n) ? cnt[idx] : 0;
    sm[threadIdx.x] = v;
    __syncthreads();
    for (int off = 1; off < SCAN_B; off <<= 1) {
        int t2 = (threadIdx.x >= off) ? sm[threadIdx.x - off] : 0;
        __syncthreads();
        sm[threadIdx.x] += t2;
        __syncthreads();
    }
    if (idx < n) part[idx] = sm[threadIdx.x];
    if (threadIdx.x == SCAN_B - 1) bsum[blockIdx.x] = sm[threadIdx.x];
}

__global__ void scan2_k(int* __restrict__ bsum, int nb)
{
    __shared__ int sm[SCAN_B];
    const int t = threadIdx.x;
    int v = (t < nb) ? bsum[t] : 0;
    sm[t] = v;
    __syncthreads();
    for (int off = 1; off < SCAN_B; off <<= 1) {
        int t2 = (t >= off) ? sm[t - off] : 0;
        __syncthreads();
        sm[t] += t2;
        __syncthreads();
    }
    if (t < nb) bsum[t] = sm[t] - v;   // exclusive
}

__global__ void scan3_k(const int* __restrict__ part, const int* __restrict__ boff,
                        int* __restrict__ offs, int n)
{
    const int idx = blockIdx.x * SCAN_B + threadIdx.x;
    if (idx < n) offs[idx + 1] = part[idx] + boff[idx / SCAN_B];
    if (idx == 0) offs[0] = 0;
}

__global__ void scatter_k(const int* __restrict__ esrc, const int* __restrict__ edst,
                          const int* __restrict__ offs, int* __restrict__ fill,
                          int* __restrict__ csr, int E_, int N_)
{
    const int i = blockIdx.x * 256 + threadIdx.x;
    if (i >= E_ + N_) return;
    int s, d;
    if (i < E_) { s = esrc[i]; d = edst[i]; } else { s = d = i - E_; }
    const int pos = offs[d] + atomicAdd(&fill[d], 1);
    csr[pos] = s;
}

// ---------------------------------------------------------------- softmax+aggregate+BN(+ReLU)
// one wave per dst node; pass 3 unrolled x4 for memory-level parallelism.
template<int CH, int C, bool RELU>
__global__ __launch_bounds__(256) void agg_k(
    const u16* __restrict__ hsrc, const int* __restrict__ offs,
    const int* __restrict__ csr, const float* __restrict__ als,
    const float* __restrict__ ald, const float* __restrict__ bias,
    const float* __restrict__ gam, const float* __restrict__ bet,
    const float* __restrict__ rmean, const float* __restrict__ rvar,
    u16* __restrict__ outp, int N)
{
    constexpr int HH = CH / C;
    constexpr int Kc = CH / 64;
    const int lane = threadIdx.x & 63;
    const int dst = blockIdx.x * 4 + (threadIdx.x >> 6);
    if (dst >= N) return;
    const int ch0 = Kc * lane;
    const int hd = ch0 / C;

    float adv[HH];
#pragma unroll
    for (int h = 0; h < HH; ++h) adv[h] = ald[(size_t)dst * HH + h];

    const int rs = offs[dst], re = offs[dst + 1];

    // pass 1: per-head max (lane-parallel over edges)
    float m[HH];
#pragma unroll
    for (int h = 0; h < HH; ++h) m[h] = -1e30f;
    for (int s = rs + lane; s < re; s += 64) {
        const int sn = csr[s];
        if constexpr (HH == 4) {
            const float4 av = *reinterpret_cast<const float4*>(&als[(size_t)sn * 4]);
            const float ev[4] = {av.x + adv[0], av.y + adv[1], av.z + adv[2], av.w + adv[3]};
#pragma unroll
            for (int h = 0; h < 4; ++h) {
                float e = ev[h]; e = (e > 0.f) ? e : 0.2f * e;
                m[h] = fmaxf(m[h], e);
            }
        } else {
            float e = als[sn] + adv[0]; e = (e > 0.f) ? e : 0.2f * e;
            m[0] = fmaxf(m[0], e);
        }
    }
#pragma unroll
    for (int h = 0; h < HH; ++h)
#pragma unroll
        for (int off = 32; off; off >>= 1) m[h] = fmaxf(m[h], __shfl_xor(m[h], off, 64));

    // pass 2: per-head denom
    float smv[HH];
#pragma unroll
    for (int h = 0; h < HH; ++h) smv[h] = 0.f;
    for (int s = rs + lane; s < re; s += 64) {
        const int sn = csr[s];
        if constexpr (HH == 4) {
            const float4 av = *reinterpret_cast<const float4*>(&als[(size_t)sn * 4]);
            const float ev[4] = {av.x + adv[0], av.y + adv[1], av.z + adv[2], av.w + adv[3]};
#pragma unroll
            for (int h = 0; h < 4; ++h) {
                float e = ev[h]; e = (e > 0.f) ? e : 0.2f * e;
                smv[h] += __expf(e - m[h]);
            }
        } else {
            float e = als[sn] + adv[0]; e = (e > 0.f) ? e : 0.2f * e;
            smv[0] += __expf(e - m[0]);
        }
    }
#pragma unroll
    for (int h = 0; h < HH; ++h)
#pragma unroll
        for (int off = 32; off; off >>= 1) smv[h] += __shfl_xor(smv[h], off, 64);
    float inv[HH];
#pragma unroll
    for (int h = 0; h < HH; ++h) inv[h] = 1.f / (smv[h] + 1e-16f);

    const float mh = m[hd], invh = inv[hd], advh = adv[hd];

    // pass 3: weighted gather, 4 edges in flight
    float acc[Kc] = {};
    int s = rs;
    for (; s + 4 <= re; s += 4) {
        int sn[4];
#pragma unroll
        for (int u = 0; u < 4; ++u) sn[u] = csr[s + u];
        if constexpr (Kc == 8) {
            int4 r[4];
#pragma unroll
            for (int u = 0; u < 4; ++u)
                r[u] = *reinterpret_cast<const int4*>(hsrc + (size_t)sn[u] * CH + ch0);
            float aa[4];
#pragma unroll
            for (int u = 0; u < 4; ++u) {
                float e = als[(size_t)sn[u] * HH + hd] + advh;
                e = (e > 0.f) ? e : 0.2f * e;
                aa[u] = __expf(e - mh) * invh;
            }
#pragma unroll
            for (int u = 0; u < 4; ++u) {
                const u32 rr2[4] = {(u32)r[u].x, (u32)r[u].y, (u32)r[u].z, (u32)r[u].w};
#pragma unroll
                for (int qq = 0; qq < 4; ++qq) {
                    acc[2*qq]   += aa[u] * bf2f(rr2[qq] & 0xffffu);
                    acc[2*qq+1] += aa[u] * bf2f(rr2[qq] >> 16);
                }
            }
        } else {
            u32 r[4];
#pragma unroll
            for (int u = 0; u < 4; ++u)
                r[u] = *reinterpret_cast<const u32*>(hsrc + (size_t)sn[u] * CH + ch0);
            float aa[4];
#pragma unroll
            for (int u = 0; u < 4; ++u) {
                float e = als[sn[u]] + advh;
                e = (e > 0.f) ? e : 0.2f * e;
                aa[u] = __expf(e - mh) * invh;
            }
#pragma unroll
            for (int u = 0; u < 4; ++u) {
                acc[0] += aa[u] * bf2f(r[u] & 0xffffu);
                acc[1] += aa[u] * bf2f(r[u] >> 16);
            }
        }
    }
    for (; s < re; ++s) {
        const int sn = csr[s];
        float e = als[(size_t)sn * HH + hd] + advh;
        e = (e > 0.f) ? e : 0.2f * e;
        const float a = __expf(e - mh) * invh;
        const u16* hp = hsrc + (size_t)sn * CH + ch0;
        if constexpr (Kc == 8) {
            const int4 r = *reinterpret_cast<const int4*>(hp);
            const u32 rr2[4] = {(u32)r.x, (u32)r.y, (u32)r.z, (u32)r.w};
#pragma unroll
            for (int qq = 0; qq < 4; ++qq) {
                acc[2*qq]   += a * bf2f(rr2[qq] & 0xffffu);
                acc[2*qq+1] += a * bf2f(rr2[qq] >> 16);
            }
        } else {
            const u32 r = *reinterpret_cast<const u32*>(hp);
            acc[0] += a * bf2f(r & 0xffffu);
            acc[1] += a * bf2f(r >> 16);
        }
    }

    // epilogue: +bias, BN (eval), optional ReLU, store bf16
    u16 ob[Kc];
#pragma unroll
    for (int j = 0; j < Kc; ++j) {
        const int ch = ch0 + j;
        const float scale = gam[ch] * rsqrtf(rvar[ch] + 1e-5f);
        float val = (acc[j] + bias[ch] - rmean[ch]) * scale + bet[ch];
        if (RELU) val = fmaxf(val, 0.f);
        ob[j] = f2bf(val);
    }
    u16* op = outp + (size_t)dst * CH + ch0;
    if constexpr (Kc == 8) {
        int4 w;
        w.x = (int)((u32)ob[0] | ((u32)ob[1] << 16));
        w.y = (int)((u32)ob[2] | ((u32)ob[3] << 16));
        w.z = (int)((u32)ob[4] | ((u32)ob[5] << 16));
        w.w = (int)((u32)ob[6] | ((u32)ob[7] << 16));
        *reinterpret_cast<int4*>(op) = w;
    } else {
        *reinterpret_cast<u32*>(op) = (u32)ob[0] | ((u32)ob[1] << 16);
    }
}

// ---------------------------------------------------------------- pool
__global__ __launch_bounds__(128) void pool_k(
    const u16* __restrict__ h3, const int* __restrict__ batch,
    float* __restrict__ out, int N)
{
    const int g = blockIdx.x;
    const int t = threadIdx.x;
    int lo = 0, hi = N;
    while (lo < hi) { int mid = (lo + hi) >> 1; if (batch[mid] < g) lo = mid + 1; else hi = mid; }
    const int s0 = lo;
    lo = 0; hi = N;
    while (lo < hi) { int mid = (lo + hi) >> 1; if (batch[mid] < g + 1) lo = mid + 1; else hi = mid; }
    const int s1 = lo;
    float sum = 0.f, mx = -1e30f;
    for (int n = s0; n < s1; ++n) {
        const float v = bf2f((u32)h3[(size_t)n * 128 + t]);
        sum += v;
        mx = fmaxf(mx, v);
    }
    const int cnt = s1 - s0;
    out[(size_t)g * 256 + t]       = cnt ? sum / (float)cnt : 0.f;
    out[(size_t)g * 256 + 128 + t] = cnt ? mx : 0.f;
}

// ---------------------------------------------------------------- launch
extern "C" void kernel_launch(void* const* d_in, const int* in_sizes, int n_in,
                              void* d_out, int out_size, void* d_ws, size_t ws_size,
                              hipStream_t stream)
{
    const float* x   = (const float*)d_in[0];
    const int* ei    = (const int*)d_in[1];
    const int* batch = (const int*)d_in[2];
    const float* W1  = (const float*)d_in[3];
    const float* as1 = (const float*)d_in[4];
    const float* ad1 = (const float*)d_in[5];
    const float* b1  = (const float*)d_in[6];
    const float* g1  = (const float*)d_in[7];
    const float* bt1 = (const float*)d_in[8];
    const float* rm1 = (const float*)d_in[9];
    const float* rv1 = (const float*)d_in[10];
    const float* W2  = (const float*)d_in[11];
    const float* as2 = (const float*)d_in[12];
    const float* ad2 = (const float*)d_in[13];
    const float* b2  = (const float*)d_in[14];
    const float* g2  = (const float*)d_in[15];
    const float* bt2 = (const float*)d_in[16];
    const float* rm2 = (const float*)d_in[17];
    const float* rv2 = (const float*)d_in[18];
    const float* W3  = (const float*)d_in[19];
    const float* as3 = (const float*)d_in[20];
    const float* ad3 = (const float*)d_in[21];
    const float* b3  = (const float*)d_in[22];
    const float* g3  = (const float*)d_in[23];
    const float* bt3 = (const float*)d_in[24];
    const float* rm3 = (const float*)d_in[25];
    const float* rv3 = (const float*)d_in[26];

    const int Nn = in_sizes[2];           // 50000
    const int Ee = in_sizes[1] / 2;       // 400000
    const int ET = Ee + Nn;               // + self-loops
    const int Gg = out_size / 256;        // 512
    const int Mp = 392 * 128;             // 50176: 392 row-panels = 8 XCDs x 49

    // workspace carve-up (256B aligned)
    char* ws = (char*)d_ws;
    size_t o = 0;
    auto alc = [&](size_t bytes) { size_t r = o; o = (o + bytes + 255) & ~(size_t)255; return r; };
    u16*  hA   = (u16*)(ws + alc((size_t)Mp * 512 * 2));
    u16*  hB   = (u16*)(ws + alc((size_t)Mp * 512 * 2));
    u16*  xb   = (u16*)(ws + alc((size_t)Mp * 96 * 2));
    u16*  Wt1  = (u16*)(ws + alc((size_t)512 * 96 * 2));
    u16*  Wt2  = (u16*)(ws + alc((size_t)512 * 512 * 2));
    u16*  Wt3  = (u16*)(ws + alc((size_t)128 * 512 * 2));
    float* als = (float*)(ws + alc((size_t)Nn * 4 * 4));
    float* ald = (float*)(ws + alc((size_t)Nn * 4 * 4));
    int*  cnt  = (int*)(ws + alc((size_t)2 * Nn * 4));
    int*  fill = cnt + Nn;
    int*  offs = (int*)(ws + alc((size_t)(Nn + 1) * 4));
    int*  part = (int*)(ws + alc((size_t)Nn * 4));
    int*  bsum = (int*)(ws + alc((size_t)SCAN_B * 4));
    int*  csr  = (int*)(ws + alc((size_t)ET * 4));
    (void)ws_size; (void)n_in;

    // ---- CSR by dst
    hipMemsetAsync(cnt, 0, (size_t)2 * Nn * 4, stream);
    const int ETB = (ET + 255) / 256;
    count_k<<<ETB, 256, 0, stream>>>(ei + Ee, cnt, Ee, Nn);
    const int nb = (Nn + SCAN_B - 1) / SCAN_B;
    scan1_k<<<nb, SCAN_B, 0, stream>>>(cnt, part, bsum, Nn);
    scan2_k<<<1, SCAN_B, 0, stream>>>(bsum, nb);
    scan3_k<<<nb, SCAN_B, 0, stream>>>(part, bsum, offs, Nn);
    scatter_k<<<ETB, 256, 0, stream>>>(ei, ei + Ee, offs, fill, csr, Ee, Nn);

    // ---- bf16 prep
    cvtx_k<<<(Mp * 96 + 255) / 256, 256, 0, stream>>>(x, xb, Nn, Mp);
    cvtw_k<<<(512 * 96 + 255) / 256, 256, 0, stream>>>(W1, Wt1, 75, 96, 512);
    cvtw_k<<<(512 * 512 + 255) / 256, 256, 0, stream>>>(W2, Wt2, 512, 512, 512);
    cvtw_k<<<(128 * 512 + 255) / 256, 256, 0, stream>>>(W3, Wt3, 512, 512, 128);

    const int nwb = (Nn + 3) / 4;
    const int nwg4 = 392 * 4;   // layers 1,2 (N=512, 4 col-blocks)
    const int nwg1 = 392;       // layer 3 (N=128)

    // ---- layer 1: GAT(75 -> 4x128, concat) + BN + ReLU
    mgemm_k<<<nwg4, 256, 0, stream>>>(xb, Wt1, hA, as1, ad1, als, ald, Nn, 96, 512, 4, 4);
    agg_k<512, 128, true><<<nwb, 256, 0, stream>>>(hA, offs, csr, als, ald,
                                                   b1, g1, bt1, rm1, rv1, hB, Nn);
    // ---- layer 2: GAT(512 -> 4x128, concat) + BN + ReLU
    mgemm_k<<<nwg4, 256, 0, stream>>>(hB, Wt2, hA, as2, ad2, als, ald, Nn, 512, 512, 4, 4);
    agg_k<512, 128, true><<<nwb, 256, 0, stream>>>(hA, offs, csr, als, ald,
                                                   b2, g2, bt2, rm2, rv2, hB, Nn);
    // ---- layer 3: GAT(512 -> 1x128, mean) + BN (no ReLU)
    mgemm_k<<<nwg1, 256, 0, stream>>>(hB, Wt3, hA, as3, ad3, als, ald, Nn, 512, 128, 1, 1);
    agg_k<128, 128, false><<<nwb, 256, 0, stream>>>(hA, offs, csr, als, ald,
                                                    b3, g3, bt3, rm3, rv3, hB, Nn);
    // ---- global mean+max pool
    pool_k<<<Gg, 128, 0, stream>>>(hB, batch, (float*)d_out, Nn);
}